// Round 17
// baseline (200.781 us; speedup 1.0000x reference)
//
#include <hip/hip_runtime.h>
#include <cstdint>
#include <cstddef>

typedef unsigned short u16;
typedef short bf16x8 __attribute__((ext_vector_type(8)));
typedef float f32x4 __attribute__((ext_vector_type(4)));

#define MFMA(a,b,c) __builtin_amdgcn_mfma_f32_16x16x32_bf16(a,b,c,0,0,0)

__device__ __forceinline__ u16 f2bf(float f) {
  unsigned u = __builtin_bit_cast(unsigned, f);
  u += 0x7fffu + ((u >> 16) & 1u);
  return (u16)(u >> 16);
}
__device__ __forceinline__ float bf2f(u16 b) {
  return __builtin_bit_cast(float, (unsigned)b << 16);
}
__device__ __forceinline__ float exp2_hw(float x) {
  float r;
  asm("v_exp_f32 %0, %1" : "=v"(r) : "v"(x));
  return r;
}
__device__ __forceinline__ void gl_lds16(const void* g, void* l) {
  __builtin_amdgcn_global_load_lds(
      (const __attribute__((address_space(1))) void*)g,
      (__attribute__((address_space(3))) void*)l, 16, 0, 0);
}
template <int N>
__device__ __forceinline__ void wait_vmcnt() {
  if constexpr (N == 0) asm volatile("s_waitcnt vmcnt(0)" ::: "memory");
  else if constexpr (N == 2) asm volatile("s_waitcnt vmcnt(2)" ::: "memory");
  else if constexpr (N == 4) asm volatile("s_waitcnt vmcnt(4)" ::: "memory");
}
__device__ __forceinline__ void block_barrier() {
  __builtin_amdgcn_sched_barrier(0);
  __builtin_amdgcn_s_barrier();
  __builtin_amdgcn_sched_barrier(0);
}

// ------- fused f32->bf16 convert for all 5 inputs + RoPE table in tail blocks -------
__global__ __launch_bounds__(256) void cvt_all(const float* __restrict__ x,
                                               const float* __restrict__ wq,
                                               const float* __restrict__ wk,
                                               const float* __restrict__ wv,
                                               const float* __restrict__ wo,
                                               u16* __restrict__ xb,
                                               u16* __restrict__ wqkvb,
                                               u16* __restrict__ wob,
                                               float* __restrict__ ctab,
                                               float* __restrict__ stab) {
  if (blockIdx.x >= 18432) {
    int i = ((blockIdx.x - 18432) * 256 + threadIdx.x) * 2;
#pragma unroll
    for (int u = 0; u < 2; ++u) {
      int e = i + u;
      int t = e >> 6, f = e & 63;
      float inv_freq = powf(10000.0f, -(2.0f * f) / 128.0f);
      float ang = (float)t * inv_freq;
      ctab[e] = cosf(ang);
      stab[e] = sinf(ang);
    }
    return;
  }
  int idx = (blockIdx.x * 256 + threadIdx.x) * 4;
  const float* src;
  u16* dst;
  if (idx < 8388608) { src = x + idx; dst = xb + idx; }
  else if (idx < 12582912) { src = wq + (idx - 8388608); dst = wqkvb + (idx - 8388608); }
  else if (idx < 13631488) { src = wk + (idx - 12582912); dst = wqkvb + (idx - 8388608); }
  else if (idx < 14680064) { src = wv + (idx - 13631488); dst = wqkvb + (idx - 8388608); }
  else { src = wo + (idx - 14680064); dst = wob + (idx - 14680064); }
  float4 v = *(const float4*)src;
  ushort4 o = {f2bf(v.x), f2bf(v.y), f2bf(v.z), f2bf(v.w)};
  *(ushort4*)dst = o;
}

// ============ m97-style NT GEMM: 128x128 tile, BK=64, 4 waves, single LDS buffer ============
// NOTE: (256,4) is load-bearing — (256,5) forces VGPR<=~100 and spills acc (R15: 2.6x slower).
template <int OUT_F32>
__global__ __launch_bounds__(256, 4) void gemm_m97(const u16* __restrict__ A,
                                                   const u16* __restrict__ Bw,
                                                   void* __restrict__ Cout,
                                                   int M, int N, int K) {
  __shared__ u16 As[128 * 64];   // 128 rows x 128B, swizzled
  __shared__ u16 Bs[128 * 64];
  const int tid = threadIdx.x;
  const int lane = tid & 63;
  const int wv = tid >> 6;           // 0..3
  const int l16 = lane & 15, lhi = lane >> 4;
  const int wm = wv >> 1, wn = wv & 1;   // 2x2 waves, each 64x64 output
  const int m0 = blockIdx.y * 128;
  const int n0 = blockIdx.x * 128;
  const int nt = K >> 6;

  const int srow8 = lane >> 3;
  const int scol = ((lane & 7) * 16) ^ (srow8 << 4);

  f32x4 acc[4][4] = {};

  for (int t = 0; t < nt; ++t) {
#pragma unroll
    for (int c = 0; c < 4; ++c) {
      int g = wv + 4 * c;
      int rowA = m0 + g * 8 + srow8;
      gl_lds16((const char*)A + ((size_t)rowA * K + (size_t)t * 64) * 2 + scol,
               (char*)As + g * 1024);
      int rowB = n0 + g * 8 + srow8;
      gl_lds16((const char*)Bw + ((size_t)rowB * K + (size_t)t * 64) * 2 + scol,
               (char*)Bs + g * 1024);
    }
    __syncthreads();
#pragma unroll
    for (int kk = 0; kk < 2; ++kk) {
      bf16x8 af[4], bfr[4];
#pragma unroll
      for (int mi = 0; mi < 4; ++mi) {
        int row = wm * 64 + mi * 16 + l16;
        af[mi] = *(const bf16x8*)((const char*)As + row * 128 +
                                  ((kk * 64 + lhi * 16) ^ ((l16 & 7) << 4)));
      }
#pragma unroll
      for (int ni = 0; ni < 4; ++ni) {
        int row = wn * 64 + ni * 16 + l16;
        bfr[ni] = *(const bf16x8*)((const char*)Bs + row * 128 +
                                   ((kk * 64 + lhi * 16) ^ ((l16 & 7) << 4)));
      }
      __builtin_amdgcn_s_setprio(1);
#pragma unroll
      for (int mi = 0; mi < 4; ++mi)
#pragma unroll
        for (int ni = 0; ni < 4; ++ni)
          acc[mi][ni] = MFMA(af[mi], bfr[ni], acc[mi][ni]);
      __builtin_amdgcn_s_setprio(0);
    }
    __syncthreads();
  }

#pragma unroll
  for (int mi = 0; mi < 4; ++mi)
#pragma unroll
    for (int ni = 0; ni < 4; ++ni) {
      int col = n0 + wn * 64 + ni * 16 + l16;
#pragma unroll
      for (int j = 0; j < 4; ++j) {
        int row = m0 + wm * 64 + mi * 16 + lhi * 4 + j;
        float v = acc[mi][ni][j];
        if (OUT_F32)
          ((float*)Cout)[(size_t)row * N + col] = v;
        else
          ((u16*)Cout)[(size_t)row * N + col] = f2bf(v);
      }
    }
}

// ---------------- RoPE + L2 norm + gamma, Q and K in ONE launch ----------------
__global__ __launch_bounds__(256) void rope_norm_qk(const u16* __restrict__ raw,
                                                    u16* __restrict__ qout,
                                                    u16* __restrict__ kout,
                                                    const float* __restrict__ ctab,
                                                    const float* __restrict__ stab,
                                                    const float* __restrict__ gq,
                                                    const float* __restrict__ gk,
                                                    float qscale) {
  const bool isQ = blockIdx.x < 16384;
  const int bid = isQ ? blockIdx.x : (blockIdx.x - 16384);
  const int NH = isQ ? 16 : 4;
  const int coloff = isQ ? 0 : 2048;
  const float scale = isQ ? qscale : 1.0f;
  const float* gamma = isQ ? gq : gk;
  u16* out = isQ ? qout : kout;

  int gw = bid * 4 + (threadIdx.x >> 6);
  int lane = threadIdx.x & 63;
  int h = gw & (NH - 1);
  int bt = gw / NH;               // 0..4095
  int t = bt & 2047, bb = bt >> 11;
  const u16* r = raw + (size_t)bt * 3072 + coloff + (size_t)h * 128;
  ushort2 own = *(const ushort2*)(r + 2 * lane);
  int pk = __shfl_xor(__builtin_bit_cast(int, own), 32);
  ushort2 par = __builtin_bit_cast(ushort2, pk);
  float x0 = bf2f(own.x), x1 = bf2f(own.y);
  float y0 = bf2f(par.x), y1 = bf2f(par.y);
  int f = (lane & 31) * 2;
  float2 c2 = *(const float2*)(ctab + t * 64 + f);
  float2 s2 = *(const float2*)(stab + t * 64 + f);
  bool hi = lane >= 32;
  float e0 = hi ? (x0 * c2.x + y0 * s2.x) : (x0 * c2.x - y0 * s2.x);
  float e1 = hi ? (x1 * c2.y + y1 * s2.y) : (x1 * c2.y - y1 * s2.y);
  float ss = e0 * e0 + e1 * e1;
#pragma unroll
  for (int off = 1; off < 64; off <<= 1) ss += __shfl_xor(ss, off);
  float inv = scale / (sqrtf(ss) + 1e-6f);
  float2 g2 = *(const float2*)(gamma + 2 * lane);
  size_t ob = (((size_t)(bb * NH + h)) * 2048 + t) * 128 + 2 * lane;
  ushort2 o = {f2bf(e0 * inv * g2.x), f2bf(e1 * inv * g2.y)};
  *(ushort2*)(out + ob) = o;
}

// ---------------- V transpose with sigma-permuted columns (32-wide groups) ----------------
// sigma for KVBLK=32: storage elem c = l*2 + n where kv = n*16 + l (n in 0..1).
__global__ __launch_bounds__(256) void transpose_v(const u16* __restrict__ qkv,
                                                   u16* __restrict__ vt) {
  __shared__ u16 tile[32][33];
  int t0 = blockIdx.x * 32, d0 = blockIdx.y * 32;
  int bh = blockIdx.z;
  int b = bh >> 2, hkk = bh & 3;
  int tx = threadIdx.x & 31, ty = threadIdx.x >> 5;  // ty 0..7
#pragma unroll
  for (int i = 0; i < 4; ++i) {
    int r = ty + i * 8;
    tile[r][tx] = qkv[((size_t)(b * 2048 + t0 + r)) * 3072 + 2560 + hkk * 128 + d0 + tx];
  }
  __syncthreads();
#pragma unroll
  for (int i = 0; i < 4; ++i) {
    int r = ty + i * 8;                 // d within 32
    int tg = t0 + tx;                   // actual kv position
    int n = (tg >> 4) & 1, l = tg & 15;
    int colp = (tg & ~31) + l * 2 + n;
    vt[((size_t)((b * 4 + hkk) * 128 + d0 + r)) * 2048 + colp] = tile[tx][r];
  }
}

// ---------------- flash attention, sliding window 1024, QBLK=128, KVBLK=32 ----------------
// 40KB LDS -> 4 blocks/CU (32 waves/CU). K+V double-buffered (swizzled), counted-vmcnt
// gates, log2-domain softmax with wave-shared base + lazy max, sigma-permuted packed P,
// rowsum via ones-MFMA, XCD-aware block remap.
__global__ __launch_bounds__(512, 4) void attn_kernel(const u16* __restrict__ Qr,
                                                      const u16* __restrict__ Kr,
                                                      const u16* __restrict__ Vt,
                                                      u16* __restrict__ Yt) {
  __shared__ u16 Ks[2][32 * 128];   // 8KB each: 32 rows x 256B, (row&7) swizzle
  __shared__ u16 Vs[2][128 * 32];   // 8KB each: 128 rows x 64B, (row&3) swizzle
  __shared__ u16 Ps[8][16 * 32];    // 1KB/wave: 16 rows x 64B, (R&3) swizzle
  const int tid = threadIdx.x;
  const int lane = tid & 63;
  const int wv = tid >> 6;
  const int l16 = lane & 15, lhi = lane >> 4;
  const int work = (blockIdx.x & 7) * 64 + (blockIdx.x >> 3);
  const int q0b = (work & 15) << 7;
  const int bh = work >> 4;
  const int b = bh >> 4, h = bh & 15;
  const int hk = h >> 2;
  const int q0w = q0b + wv * 16;

  const u16* qbase = Qr + (((size_t)bh) * 2048 + q0w + l16) * 128;
  bf16x8 qf[4];
#pragma unroll
  for (int dc = 0; dc < 4; ++dc)
    qf[dc] = *(const bf16x8*)(qbase + dc * 32 + lhi * 8);

  const char* kg = (const char*)(Kr + ((size_t)(b * 4 + hk)) * 2048 * 128);
  const u16* vg = Vt + ((size_t)(b * 4 + hk)) * 2048 * 128;

  auto stage = [&](int buf, int s0) {   // 2 gl_lds per wave
    {
      int row = wv * 4 + lhi;           // K: chunk wv = 4 rows of 256B
      int srcb = (l16 * 16) ^ ((row & 7) << 4);
      gl_lds16(kg + (size_t)(s0 + row) * 256 + srcb, (char*)Ks[buf] + wv * 1024);
    }
    {
      int r16 = lane >> 2, c4 = lane & 3;  // V: chunk wv = 16 rows of 64B
      int row = wv * 16 + r16;
      gl_lds16((const char*)(vg + (size_t)row * 2048 + s0) + ((c4 ^ (r16 & 3)) << 4),
               (char*)Vs[buf] + wv * 1024);
    }
  };

  const bf16x8 ones = {0x3F80, 0x3F80, 0x3F80, 0x3F80, 0x3F80, 0x3F80, 0x3F80, 0x3F80};
  float mbase = 0.f;
  f32x4 lacc = {};
  f32x4 oacc[8] = {};

  int s_lo = q0b - 1024; if (s_lo < 0) s_lo = 0;
  const int nt = (q0b + 128 - s_lo) >> 5;

  stage(0, s_lo);
  int cur = 0;
  for (int it = 0; it < nt; ++it) {
    const int s0 = s_lo + (it << 5);
    if (it + 1 < nt) {
      stage(cur ^ 1, s0 + 32);
      wait_vmcnt<2>();
    } else {
      wait_vmcnt<0>();
    }
    block_barrier();
    const bool skip = (q0w + 15 < s0) || (q0w - (s0 + 31) > 1024);
    if (!skip) {
      // QK^T (8 MFMA)
      f32x4 sacc[2] = {};
      const char* ksb = (const char*)Ks[cur];
      __builtin_amdgcn_s_setprio(1);
#pragma unroll
      for (int n = 0; n < 2; ++n) {
        int row = n * 16 + l16;
#pragma unroll
        for (int dc = 0; dc < 4; ++dc) {
          bf16x8 kf = *(const bf16x8*)(ksb + row * 256 +
                                       ((dc * 64 + lhi * 16) ^ ((l16 & 7) << 4)));
          sacc[n] = MFMA(qf[dc], kf, sacc[n]);
        }
      }
      __builtin_amdgcn_s_setprio(0);
      const bool domask = (q0w < s0 + 31) || (q0w + 15 - s0 > 1024);
      if (domask) {
#pragma unroll
        for (int n = 0; n < 2; ++n)
#pragma unroll
          for (int j = 0; j < 4; ++j) {
            int q = q0w + lhi * 4 + j;
            int s = s0 + n * 16 + l16;
            if ((unsigned)(q - s) > 1024u) sacc[n][j] = -INFINITY;
          }
      }
      // lazy max
      float lm = sacc[0][0];
#pragma unroll
      for (int n = 0; n < 2; ++n)
#pragma unroll
        for (int j = 0; j < 4; ++j) lm = fmaxf(lm, sacc[n][j]);
      if (__any(lm > mbase + 8.f)) {
        float mt = lm;
#pragma unroll
        for (int off = 1; off < 64; off <<= 1) mt = fmaxf(mt, __shfl_xor(mt, off));
        float sc2 = exp2_hw(mbase - mt);
#pragma unroll
        for (int j = 0; j < 4; ++j) lacc[j] *= sc2;
#pragma unroll
        for (int dt = 0; dt < 8; ++dt)
#pragma unroll
          for (int j = 0; j < 4; ++j) oacc[dt][j] *= sc2;
        mbase = mt;
      }
      // P: sigma-permuted packed writes (elem c = l16*2 + n; kv = n*16 + l16)
      char* psb = (char*)Ps[wv];
#pragma unroll
      for (int j = 0; j < 4; ++j) {
        int R = lhi * 4 + j;
        float p0 = exp2_hw(sacc[0][j] - mbase);
        float p1 = exp2_hw(sacc[1][j] - mbase);
        unsigned r01;
        asm("v_cvt_pk_bf16_f32 %0, %1, %2" : "=v"(r01) : "v"(p0), "v"(p1));
        *(unsigned*)(psb + R * 64 + ((l16 * 4) ^ ((R & 3) << 4))) = r01;
      }
      // PV + rowsum (9 MFMA); V content sigma-permuted to match
      bf16x8 pf = *(const bf16x8*)(psb + l16 * 64 + ((lhi * 16) ^ ((l16 & 3) << 4)));
      const char* vsb = (const char*)Vs[cur];
      __builtin_amdgcn_s_setprio(1);
      lacc = MFMA(pf, ones, lacc);
#pragma unroll
      for (int dt = 0; dt < 8; ++dt) {
        int row = dt * 16 + l16;
        bf16x8 vf = *(const bf16x8*)(vsb + row * 64 +
                                     ((lhi * 16) ^ ((row & 3) << 4)));
        oacc[dt] = MFMA(pf, vf, oacc[dt]);
      }
      __builtin_amdgcn_s_setprio(0);
    }
    block_barrier();
    cur ^= 1;
  }
#pragma unroll
  for (int j = 0; j < 4; ++j) {
    float inv = 1.0f / lacc[j];
    int q = q0w + lhi * 4 + j;
    size_t rowbase = ((size_t)(b * 2048 + q)) * 2048 + (size_t)h * 128;
#pragma unroll
    for (int dt = 0; dt < 8; ++dt)
      Yt[rowbase + dt * 16 + l16] = f2bf(oacc[dt][j] * inv);
  }
}

extern "C" void kernel_launch(void* const* d_in, const int* in_sizes, int n_in,
                              void* d_out, int out_size, void* d_ws, size_t ws_size,
                              hipStream_t stream) {
  (void)in_sizes; (void)n_in; (void)out_size; (void)ws_size;
  const float* x  = (const float*)d_in[0];
  const float* wq = (const float*)d_in[1];
  const float* wk = (const float*)d_in[2];
  const float* wv = (const float*)d_in[3];
  const float* wo = (const float*)d_in[4];
  const float* gq = (const float*)d_in[5];
  const float* gk = (const float*)d_in[6];
  float* out = (float*)d_out;
  char* ws = (char*)d_ws;

  size_t off = 0;
  auto alloc = [&](size_t bytes) {
    size_t o = off;
    off += (bytes + 255) & ~(size_t)255;
    return o;
  };
  u16* xb     = (u16*)(ws + alloc((size_t)4096 * 2048 * 2));
  u16* wqkvb  = (u16*)(ws + alloc((size_t)3072 * 2048 * 2));
  u16* wob    = (u16*)(ws + alloc((size_t)2048 * 2048 * 2));
  u16* qkvraw = (u16*)(ws + alloc((size_t)4096 * 3072 * 2));  // later reused as ytmp
  u16* qr     = (u16*)(ws + alloc((size_t)4096 * 2048 * 2));
  u16* kr     = (u16*)(ws + alloc((size_t)4096 * 512 * 2));
  u16* vt     = (u16*)(ws + alloc((size_t)4096 * 512 * 2));
  float* ctab = (float*)(ws + alloc((size_t)2048 * 64 * 4));
  float* stab = (float*)(ws + alloc((size_t)2048 * 64 * 4));
  u16* ytmp = qkvraw;  // safe: qkvraw fully consumed before attn writes

  const float sc_log2 = 0.12751744f;  // 1/sqrt(128) * log2(e)

  cvt_all<<<18688, 256, 0, stream>>>(x, wq, wk, wv, wo, xb, wqkvb, wob, ctab, stab);

  gemm_m97<0><<<dim3(24, 32), 256, 0, stream>>>(xb, wqkvb, qkvraw, 4096, 3072, 2048);

  rope_norm_qk<<<20480, 256, 0, stream>>>(qkvraw, qr, kr, ctab, stab, gq, gk, sc_log2);
  transpose_v<<<dim3(64, 4, 8), 256, 0, stream>>>(qkvraw, vt);

  attn_kernel<<<dim3(512), 512, 0, stream>>>(qr, kr, vt, ytmp);

  gemm_m97<1><<<dim3(16, 32), 256, 0, stream>>>(ytmp, wob, out, 4096, 2048, 2048);
}

// Round 18
// 190.419 us; speedup vs baseline: 1.0544x; 1.0544x over previous
//
#include <hip/hip_runtime.h>
#include <cstdint>
#include <cstddef>

typedef unsigned short u16;
typedef short bf16x8 __attribute__((ext_vector_type(8)));
typedef float f32x4 __attribute__((ext_vector_type(4)));

#define MFMA(a,b,c) __builtin_amdgcn_mfma_f32_16x16x32_bf16(a,b,c,0,0,0)

__device__ __forceinline__ u16 f2bf(float f) {
  unsigned u = __builtin_bit_cast(unsigned, f);
  u += 0x7fffu + ((u >> 16) & 1u);
  return (u16)(u >> 16);
}
__device__ __forceinline__ float bf2f(u16 b) {
  return __builtin_bit_cast(float, (unsigned)b << 16);
}
__device__ __forceinline__ float exp2_hw(float x) {
  float r;
  asm("v_exp_f32 %0, %1" : "=v"(r) : "v"(x));
  return r;
}
__device__ __forceinline__ void gl_lds16(const void* g, void* l) {
  __builtin_amdgcn_global_load_lds(
      (const __attribute__((address_space(1))) void*)g,
      (__attribute__((address_space(3))) void*)l, 16, 0, 0);
}
template <int N>
__device__ __forceinline__ void wait_vmcnt() {
  if constexpr (N == 0) asm volatile("s_waitcnt vmcnt(0)" ::: "memory");
  else if constexpr (N == 4) asm volatile("s_waitcnt vmcnt(4)" ::: "memory");
}
__device__ __forceinline__ void block_barrier() {
  __builtin_amdgcn_sched_barrier(0);
  __builtin_amdgcn_s_barrier();
  __builtin_amdgcn_sched_barrier(0);
}

// ------- fused f32->bf16 convert for all 5 inputs + RoPE table in tail blocks -------
__global__ __launch_bounds__(256) void cvt_all(const float* __restrict__ x,
                                               const float* __restrict__ wq,
                                               const float* __restrict__ wk,
                                               const float* __restrict__ wv,
                                               const float* __restrict__ wo,
                                               u16* __restrict__ xb,
                                               u16* __restrict__ wqkvb,
                                               u16* __restrict__ wob,
                                               float* __restrict__ ctab,
                                               float* __restrict__ stab) {
  if (blockIdx.x >= 18432) {
    int i = ((blockIdx.x - 18432) * 256 + threadIdx.x) * 2;
#pragma unroll
    for (int u = 0; u < 2; ++u) {
      int e = i + u;
      int t = e >> 6, f = e & 63;
      float inv_freq = powf(10000.0f, -(2.0f * f) / 128.0f);
      float ang = (float)t * inv_freq;
      ctab[e] = cosf(ang);
      stab[e] = sinf(ang);
    }
    return;
  }
  int idx = (blockIdx.x * 256 + threadIdx.x) * 4;
  const float* src;
  u16* dst;
  if (idx < 8388608) { src = x + idx; dst = xb + idx; }
  else if (idx < 12582912) { src = wq + (idx - 8388608); dst = wqkvb + (idx - 8388608); }
  else if (idx < 13631488) { src = wk + (idx - 12582912); dst = wqkvb + (idx - 8388608); }
  else if (idx < 14680064) { src = wv + (idx - 13631488); dst = wqkvb + (idx - 8388608); }
  else { src = wo + (idx - 14680064); dst = wob + (idx - 14680064); }
  float4 v = *(const float4*)src;
  ushort4 o = {f2bf(v.x), f2bf(v.y), f2bf(v.z), f2bf(v.w)};
  *(ushort4*)dst = o;
}

// ============ m97-style NT GEMM: 128x128 tile, BK=64, 4 waves, single LDS buffer ============
// NOTE: (256,4) is load-bearing — (256,5) forces VGPR<=~100 and spills acc (R15: 2.6x slower).
template <int OUT_F32>
__global__ __launch_bounds__(256, 4) void gemm_m97(const u16* __restrict__ A,
                                                   const u16* __restrict__ Bw,
                                                   void* __restrict__ Cout,
                                                   int M, int N, int K) {
  __shared__ u16 As[128 * 64];   // 128 rows x 128B, swizzled
  __shared__ u16 Bs[128 * 64];
  const int tid = threadIdx.x;
  const int lane = tid & 63;
  const int wv = tid >> 6;           // 0..3
  const int l16 = lane & 15, lhi = lane >> 4;
  const int wm = wv >> 1, wn = wv & 1;   // 2x2 waves, each 64x64 output
  const int m0 = blockIdx.y * 128;
  const int n0 = blockIdx.x * 128;
  const int nt = K >> 6;

  const int srow8 = lane >> 3;
  const int scol = ((lane & 7) * 16) ^ (srow8 << 4);

  f32x4 acc[4][4] = {};

  for (int t = 0; t < nt; ++t) {
#pragma unroll
    for (int c = 0; c < 4; ++c) {
      int g = wv + 4 * c;
      int rowA = m0 + g * 8 + srow8;
      gl_lds16((const char*)A + ((size_t)rowA * K + (size_t)t * 64) * 2 + scol,
               (char*)As + g * 1024);
      int rowB = n0 + g * 8 + srow8;
      gl_lds16((const char*)Bw + ((size_t)rowB * K + (size_t)t * 64) * 2 + scol,
               (char*)Bs + g * 1024);
    }
    __syncthreads();
#pragma unroll
    for (int kk = 0; kk < 2; ++kk) {
      bf16x8 af[4], bfr[4];
#pragma unroll
      for (int mi = 0; mi < 4; ++mi) {
        int row = wm * 64 + mi * 16 + l16;
        af[mi] = *(const bf16x8*)((const char*)As + row * 128 +
                                  ((kk * 64 + lhi * 16) ^ ((l16 & 7) << 4)));
      }
#pragma unroll
      for (int ni = 0; ni < 4; ++ni) {
        int row = wn * 64 + ni * 16 + l16;
        bfr[ni] = *(const bf16x8*)((const char*)Bs + row * 128 +
                                   ((kk * 64 + lhi * 16) ^ ((l16 & 7) << 4)));
      }
      __builtin_amdgcn_s_setprio(1);
#pragma unroll
      for (int mi = 0; mi < 4; ++mi)
#pragma unroll
        for (int ni = 0; ni < 4; ++ni)
          acc[mi][ni] = MFMA(af[mi], bfr[ni], acc[mi][ni]);
      __builtin_amdgcn_s_setprio(0);
    }
    __syncthreads();
  }

#pragma unroll
  for (int mi = 0; mi < 4; ++mi)
#pragma unroll
    for (int ni = 0; ni < 4; ++ni) {
      int col = n0 + wn * 64 + ni * 16 + l16;
#pragma unroll
      for (int j = 0; j < 4; ++j) {
        int row = m0 + wm * 64 + mi * 16 + lhi * 4 + j;
        float v = acc[mi][ni][j];
        if (OUT_F32)
          ((float*)Cout)[(size_t)row * N + col] = v;
        else
          ((u16*)Cout)[(size_t)row * N + col] = f2bf(v);
      }
    }
}

// ------- RoPE+norm for Q and K, plus sigma-permuted V transpose, ONE launch -------
// blocks [0,16384): Q rope+norm; [16384,20480): K rope+norm; [20480,22528): V transpose.
__global__ __launch_bounds__(256) void rope_tr_qkv(const u16* __restrict__ raw,
                                                   u16* __restrict__ qout,
                                                   u16* __restrict__ kout,
                                                   u16* __restrict__ vt,
                                                   const float* __restrict__ ctab,
                                                   const float* __restrict__ stab,
                                                   const float* __restrict__ gq,
                                                   const float* __restrict__ gk,
                                                   float qscale) {
  __shared__ u16 tile[32][33];
  if (blockIdx.x >= 20480) {
    // ---- V transpose with sigma-permuted columns (64-wide groups) ----
    int f = blockIdx.x - 20480;          // 0..2047; orig grid (x=64,y=4,z=8)
    int t0 = (f & 63) * 32, d0 = ((f >> 6) & 3) * 32;
    int bh = f >> 8;
    int b = bh >> 2, hkk = bh & 3;
    int tx = threadIdx.x & 31, ty = threadIdx.x >> 5;  // ty 0..7
#pragma unroll
    for (int i = 0; i < 4; ++i) {
      int r = ty + i * 8;
      tile[r][tx] = raw[((size_t)(b * 2048 + t0 + r)) * 3072 + 2560 + hkk * 128 + d0 + tx];
    }
    __syncthreads();
#pragma unroll
    for (int i = 0; i < 4; ++i) {
      int r = ty + i * 8;                 // d within 32
      int tg = t0 + tx;                   // actual kv position
      int n = (tg >> 4) & 3, l = tg & 15;
      int colp = (tg & ~63) + l * 2 + (n & 1) + ((n >> 1) << 5);
      vt[((size_t)((b * 4 + hkk) * 128 + d0 + r)) * 2048 + colp] = tile[tx][r];
    }
    return;
  }
  // ---- RoPE + L2 norm + gamma ----
  const bool isQ = blockIdx.x < 16384;
  const int bid = isQ ? blockIdx.x : (blockIdx.x - 16384);
  const int NH = isQ ? 16 : 4;
  const int coloff = isQ ? 0 : 2048;
  const float scale = isQ ? qscale : 1.0f;
  const float* gamma = isQ ? gq : gk;
  u16* out = isQ ? qout : kout;

  int gw = bid * 4 + (threadIdx.x >> 6);
  int lane = threadIdx.x & 63;
  int h = gw & (NH - 1);
  int bt = gw / NH;               // 0..4095
  int t = bt & 2047, bb = bt >> 11;
  const u16* r = raw + (size_t)bt * 3072 + coloff + (size_t)h * 128;
  ushort2 own = *(const ushort2*)(r + 2 * lane);
  int pk = __shfl_xor(__builtin_bit_cast(int, own), 32);
  ushort2 par = __builtin_bit_cast(ushort2, pk);
  float x0 = bf2f(own.x), x1 = bf2f(own.y);
  float y0 = bf2f(par.x), y1 = bf2f(par.y);
  int f = (lane & 31) * 2;
  float2 c2 = *(const float2*)(ctab + t * 64 + f);
  float2 s2 = *(const float2*)(stab + t * 64 + f);
  bool hi = lane >= 32;
  float e0 = hi ? (x0 * c2.x + y0 * s2.x) : (x0 * c2.x - y0 * s2.x);
  float e1 = hi ? (x1 * c2.y + y1 * s2.y) : (x1 * c2.y - y1 * s2.y);
  float ss = e0 * e0 + e1 * e1;
#pragma unroll
  for (int off = 1; off < 64; off <<= 1) ss += __shfl_xor(ss, off);
  float inv = scale / (sqrtf(ss) + 1e-6f);
  float2 g2 = *(const float2*)(gamma + 2 * lane);
  size_t ob = (((size_t)(bb * NH + h)) * 2048 + t) * 128 + 2 * lane;
  ushort2 o = {f2bf(e0 * inv * g2.x), f2bf(e1 * inv * g2.y)};
  *(ushort2*)(out + ob) = o;
}

// ---------------- flash attention, sliding window 1024, QBLK=128, KVBLK=64 ----------------
// (R16/R13-validated version: 80KB LDS, sigma-P packed writes, lazy max.)
__global__ __launch_bounds__(512, 4) void attn_kernel(const u16* __restrict__ Qr,
                                                      const u16* __restrict__ Kr,
                                                      const u16* __restrict__ Vt,
                                                      u16* __restrict__ Yt) {
  __shared__ u16 Ks[2][64 * 128];
  __shared__ u16 Vs[2][128 * 64];
  __shared__ u16 Ps[8][16 * 64];
  const int tid = threadIdx.x;
  const int lane = tid & 63;
  const int wv = tid >> 6;
  const int l16 = lane & 15, lhi = lane >> 4;
  const int work = (blockIdx.x & 7) * 64 + (blockIdx.x >> 3);
  const int q0b = (work & 15) << 7;
  const int bh = work >> 4;
  const int b = bh >> 4, h = bh & 15;
  const int hk = h >> 2;
  const int q0w = q0b + wv * 16;

  const u16* qbase = Qr + (((size_t)bh) * 2048 + q0w + l16) * 128;
  bf16x8 qf[4];
#pragma unroll
  for (int dc = 0; dc < 4; ++dc)
    qf[dc] = *(const bf16x8*)(qbase + dc * 32 + lhi * 8);

  const char* kg = (const char*)(Kr + ((size_t)(b * 4 + hk)) * 2048 * 128);
  const u16* vg = Vt + ((size_t)(b * 4 + hk)) * 2048 * 128;

  auto stage = [&](int buf, int s0) {
#pragma unroll
    for (int i = 0; i < 2; ++i) {
      int c = wv + 8 * i;
      int row = c * 4 + lhi;
      int srcb = (l16 * 16) ^ ((row & 7) << 4);
      gl_lds16(kg + (size_t)(s0 + row) * 256 + srcb, (char*)Ks[buf] + c * 1024);
    }
    int r8 = lane >> 3, c8 = lane & 7;
#pragma unroll
    for (int i = 0; i < 2; ++i) {
      int c = wv + 8 * i;
      int row = c * 8 + r8;
      int srcb = (c8 * 16) ^ ((r8 & 7) << 4);
      gl_lds16((const char*)(vg + (size_t)row * 2048 + s0) + srcb,
               (char*)Vs[buf] + c * 1024);
    }
  };

  const bf16x8 ones = {0x3F80, 0x3F80, 0x3F80, 0x3F80, 0x3F80, 0x3F80, 0x3F80, 0x3F80};
  float mbase = 0.f;
  f32x4 lacc = {};
  f32x4 oacc[8] = {};

  int s_lo = q0b - 1024; if (s_lo < 0) s_lo = 0;
  const int nt = (q0b + 128 - s_lo) >> 6;

  stage(0, s_lo);
  int cur = 0;
  for (int it = 0; it < nt; ++it) {
    const int s0 = s_lo + (it << 6);
    if (it + 1 < nt) {
      stage(cur ^ 1, s0 + 64);
      wait_vmcnt<4>();
    } else {
      wait_vmcnt<0>();
    }
    block_barrier();
    const bool skip = (q0w + 15 < s0) || (q0w - (s0 + 63) > 1024);
    if (!skip) {
      f32x4 sacc[4] = {};
      const char* ksb = (const char*)Ks[cur];
      __builtin_amdgcn_s_setprio(1);
#pragma unroll
      for (int n = 0; n < 4; ++n) {
        int row = n * 16 + l16;
#pragma unroll
        for (int dc = 0; dc < 4; ++dc) {
          bf16x8 kf = *(const bf16x8*)(ksb + row * 256 +
                                       ((dc * 64 + lhi * 16) ^ ((l16 & 7) << 4)));
          sacc[n] = MFMA(qf[dc], kf, sacc[n]);
        }
      }
      __builtin_amdgcn_s_setprio(0);
      const bool domask = (q0w < s0 + 63) || (q0w + 15 - s0 > 1024);
      if (domask) {
#pragma unroll
        for (int n = 0; n < 4; ++n)
#pragma unroll
          for (int j = 0; j < 4; ++j) {
            int q = q0w + lhi * 4 + j;
            int s = s0 + n * 16 + l16;
            if ((unsigned)(q - s) > 1024u) sacc[n][j] = -INFINITY;
          }
      }
      float nm[4];
#pragma unroll
      for (int n = 0; n < 4; ++n)
        nm[n] = fmaxf(fmaxf(sacc[n][0], sacc[n][1]), fmaxf(sacc[n][2], sacc[n][3]));
      float lm = fmaxf(fmaxf(nm[0], nm[1]), fmaxf(nm[2], nm[3]));
      if (__any(lm > mbase + 8.f)) {
        float mt = lm;
#pragma unroll
        for (int off = 1; off < 64; off <<= 1) mt = fmaxf(mt, __shfl_xor(mt, off));
        float sc2 = exp2_hw(mbase - mt);
#pragma unroll
        for (int j = 0; j < 4; ++j) lacc[j] *= sc2;
#pragma unroll
        for (int dt = 0; dt < 8; ++dt)
#pragma unroll
          for (int j = 0; j < 4; ++j) oacc[dt][j] *= sc2;
        mbase = mt;
      }
      char* psb = (char*)Ps[wv];
#pragma unroll
      for (int j = 0; j < 4; ++j) {
        int R = lhi * 4 + j;
        float p0 = exp2_hw(sacc[0][j] - mbase);
        float p1 = exp2_hw(sacc[1][j] - mbase);
        float p2 = exp2_hw(sacc[2][j] - mbase);
        float p3 = exp2_hw(sacc[3][j] - mbase);
        unsigned r01, r23;
        asm("v_cvt_pk_bf16_f32 %0, %1, %2" : "=v"(r01) : "v"(p0), "v"(p1));
        asm("v_cvt_pk_bf16_f32 %0, %1, %2" : "=v"(r23) : "v"(p2), "v"(p3));
        *(unsigned*)(psb + R * 128 + ((l16 * 4) ^ ((R & 7) << 4))) = r01;
        *(unsigned*)(psb + R * 128 + ((64 + l16 * 4) ^ ((R & 7) << 4))) = r23;
      }
      bf16x8 pf[2];
#pragma unroll
      for (int kk = 0; kk < 2; ++kk)
        pf[kk] = *(const bf16x8*)(psb + l16 * 128 +
                                  ((kk * 64 + lhi * 16) ^ ((l16 & 7) << 4)));
      const char* vsb = (const char*)Vs[cur];
      __builtin_amdgcn_s_setprio(1);
      lacc = MFMA(pf[0], ones, lacc);
      lacc = MFMA(pf[1], ones, lacc);
#pragma unroll
      for (int dt = 0; dt < 8; ++dt) {
        int row = dt * 16 + l16;
#pragma unroll
        for (int kk = 0; kk < 2; ++kk) {
          bf16x8 vf = *(const bf16x8*)(vsb + row * 128 +
                                       ((kk * 64 + lhi * 16) ^ ((l16 & 7) << 4)));
          oacc[dt] = MFMA(pf[kk], vf, oacc[dt]);
        }
      }
      __builtin_amdgcn_s_setprio(0);
    }
    block_barrier();
    cur ^= 1;
  }
#pragma unroll
  for (int j = 0; j < 4; ++j) {
    float inv = 1.0f / lacc[j];
    int q = q0w + lhi * 4 + j;
    size_t rowbase = ((size_t)(b * 2048 + q)) * 2048 + (size_t)h * 128;
#pragma unroll
    for (int dt = 0; dt < 8; ++dt)
      Yt[rowbase + dt * 16 + l16] = f2bf(oacc[dt][j] * inv);
  }
}

extern "C" void kernel_launch(void* const* d_in, const int* in_sizes, int n_in,
                              void* d_out, int out_size, void* d_ws, size_t ws_size,
                              hipStream_t stream) {
  (void)in_sizes; (void)n_in; (void)out_size; (void)ws_size;
  const float* x  = (const float*)d_in[0];
  const float* wq = (const float*)d_in[1];
  const float* wk = (const float*)d_in[2];
  const float* wv = (const float*)d_in[3];
  const float* wo = (const float*)d_in[4];
  const float* gq = (const float*)d_in[5];
  const float* gk = (const float*)d_in[6];
  float* out = (float*)d_out;
  char* ws = (char*)d_ws;

  size_t off = 0;
  auto alloc = [&](size_t bytes) {
    size_t o = off;
    off += (bytes + 255) & ~(size_t)255;
    return o;
  };
  u16* xb     = (u16*)(ws + alloc((size_t)4096 * 2048 * 2));
  u16* wqkvb  = (u16*)(ws + alloc((size_t)3072 * 2048 * 2));
  u16* wob    = (u16*)(ws + alloc((size_t)2048 * 2048 * 2));
  u16* qkvraw = (u16*)(ws + alloc((size_t)4096 * 3072 * 2));  // later reused as ytmp
  u16* qr     = (u16*)(ws + alloc((size_t)4096 * 2048 * 2));
  u16* kr     = (u16*)(ws + alloc((size_t)4096 * 512 * 2));
  u16* vt     = (u16*)(ws + alloc((size_t)4096 * 512 * 2));
  float* ctab = (float*)(ws + alloc((size_t)2048 * 64 * 4));
  float* stab = (float*)(ws + alloc((size_t)2048 * 64 * 4));
  u16* ytmp = qkvraw;  // safe: qkvraw fully consumed before attn writes

  const float sc_log2 = 0.12751744f;  // 1/sqrt(128) * log2(e)

  cvt_all<<<18688, 256, 0, stream>>>(x, wq, wk, wv, wo, xb, wqkvb, wob, ctab, stab);

  gemm_m97<0><<<dim3(24, 32), 256, 0, stream>>>(xb, wqkvb, qkvraw, 4096, 3072, 2048);

  // RoPE+norm (Q,K) + sigma-permuted V transpose, one launch
  rope_tr_qkv<<<22528, 256, 0, stream>>>(qkvraw, qr, kr, vt, ctab, stab, gq, gk, sc_log2);

  attn_kernel<<<dim3(512), 512, 0, stream>>>(qr, kr, vt, ytmp);

  gemm_m97<1><<<dim3(16, 32), 256, 0, stream>>>(ytmp, wob, out, 4096, 2048, 2048);
}

// Round 19
// 190.385 us; speedup vs baseline: 1.0546x; 1.0002x over previous
//
#include <hip/hip_runtime.h>
#include <cstdint>
#include <cstddef>

typedef unsigned short u16;
typedef short bf16x8 __attribute__((ext_vector_type(8)));
typedef float f32x4 __attribute__((ext_vector_type(4)));

#define MFMA(a,b,c) __builtin_amdgcn_mfma_f32_16x16x32_bf16(a,b,c,0,0,0)

__device__ __forceinline__ u16 f2bf(float f) {
  unsigned u = __builtin_bit_cast(unsigned, f);
  u += 0x7fffu + ((u >> 16) & 1u);
  return (u16)(u >> 16);
}
__device__ __forceinline__ float bf2f(u16 b) {
  return __builtin_bit_cast(float, (unsigned)b << 16);
}
__device__ __forceinline__ float exp2_hw(float x) {
  float r;
  asm("v_exp_f32 %0, %1" : "=v"(r) : "v"(x));
  return r;
}
__device__ __forceinline__ void gl_lds16(const void* g, void* l) {
  __builtin_amdgcn_global_load_lds(
      (const __attribute__((address_space(1))) void*)g,
      (__attribute__((address_space(3))) void*)l, 16, 0, 0);
}
template <int N>
__device__ __forceinline__ void wait_vmcnt() {
  if constexpr (N == 0) asm volatile("s_waitcnt vmcnt(0)" ::: "memory");
  else if constexpr (N == 4) asm volatile("s_waitcnt vmcnt(4)" ::: "memory");
}
__device__ __forceinline__ void block_barrier() {
  __builtin_amdgcn_sched_barrier(0);
  __builtin_amdgcn_s_barrier();
  __builtin_amdgcn_sched_barrier(0);
}

// ------- fused f32->bf16 convert for all 5 inputs + RoPE table in tail blocks -------
__global__ __launch_bounds__(256) void cvt_all(const float* __restrict__ x,
                                               const float* __restrict__ wq,
                                               const float* __restrict__ wk,
                                               const float* __restrict__ wv,
                                               const float* __restrict__ wo,
                                               u16* __restrict__ xb,
                                               u16* __restrict__ wqkvb,
                                               u16* __restrict__ wob,
                                               float* __restrict__ ctab,
                                               float* __restrict__ stab) {
  if (blockIdx.x >= 18432) {
    int i = ((blockIdx.x - 18432) * 256 + threadIdx.x) * 2;
#pragma unroll
    for (int u = 0; u < 2; ++u) {
      int e = i + u;
      int t = e >> 6, f = e & 63;
      float inv_freq = powf(10000.0f, -(2.0f * f) / 128.0f);
      float ang = (float)t * inv_freq;
      ctab[e] = cosf(ang);
      stab[e] = sinf(ang);
    }
    return;
  }
  int idx = (blockIdx.x * 256 + threadIdx.x) * 4;
  const float* src;
  u16* dst;
  if (idx < 8388608) { src = x + idx; dst = xb + idx; }
  else if (idx < 12582912) { src = wq + (idx - 8388608); dst = wqkvb + (idx - 8388608); }
  else if (idx < 13631488) { src = wk + (idx - 12582912); dst = wqkvb + (idx - 8388608); }
  else if (idx < 14680064) { src = wv + (idx - 13631488); dst = wqkvb + (idx - 8388608); }
  else { src = wo + (idx - 14680064); dst = wob + (idx - 14680064); }
  float4 v = *(const float4*)src;
  ushort4 o = {f2bf(v.x), f2bf(v.y), f2bf(v.z), f2bf(v.w)};
  *(ushort4*)dst = o;
}

// ============ m97-style NT GEMM: 128x128 tile, BK=64, 4 waves, single LDS buffer ============
// XCD-aware chunked remap: XCD k owns nwg/8 consecutive work items (4 full A-panel rows,
// 2MB -> L2-resident A; staging loads hit L2 instead of HBM -> shorter barrier drains).
// NOTE: (256,4) is load-bearing — (256,5) forces VGPR<=~100 and spills acc (R15: 2.6x slower).
template <int OUT_F32>
__global__ __launch_bounds__(256, 4) void gemm_m97(const u16* __restrict__ A,
                                                   const u16* __restrict__ Bw,
                                                   void* __restrict__ Cout,
                                                   int M, int N, int K) {
  __shared__ u16 As[128 * 64];   // 128 rows x 128B, swizzled
  __shared__ u16 Bs[128 * 64];
  const int tid = threadIdx.x;
  const int lane = tid & 63;
  const int wv = tid >> 6;           // 0..3
  const int l16 = lane & 15, lhi = lane >> 4;
  const int wm = wv >> 1, wn = wv & 1;   // 2x2 waves, each 64x64 output

  // XCD chunked swizzle (bijective: nwg % 8 == 0 for both 768 and 512)
  const int nbx = N >> 7;
  const int nwg = (M >> 7) * nbx;
  const int cpx = nwg >> 3;
  const int swz = (blockIdx.x & 7) * cpx + (blockIdx.x >> 3);
  const int m0 = (swz / nbx) * 128;
  const int n0 = (swz % nbx) * 128;
  const int nt = K >> 6;

  const int srow8 = lane >> 3;
  const int scol = ((lane & 7) * 16) ^ (srow8 << 4);

  f32x4 acc[4][4] = {};

  for (int t = 0; t < nt; ++t) {
#pragma unroll
    for (int c = 0; c < 4; ++c) {
      int g = wv + 4 * c;
      int rowA = m0 + g * 8 + srow8;
      gl_lds16((const char*)A + ((size_t)rowA * K + (size_t)t * 64) * 2 + scol,
               (char*)As + g * 1024);
      int rowB = n0 + g * 8 + srow8;
      gl_lds16((const char*)Bw + ((size_t)rowB * K + (size_t)t * 64) * 2 + scol,
               (char*)Bs + g * 1024);
    }
    __syncthreads();
#pragma unroll
    for (int kk = 0; kk < 2; ++kk) {
      bf16x8 af[4], bfr[4];
#pragma unroll
      for (int mi = 0; mi < 4; ++mi) {
        int row = wm * 64 + mi * 16 + l16;
        af[mi] = *(const bf16x8*)((const char*)As + row * 128 +
                                  ((kk * 64 + lhi * 16) ^ ((l16 & 7) << 4)));
      }
#pragma unroll
      for (int ni = 0; ni < 4; ++ni) {
        int row = wn * 64 + ni * 16 + l16;
        bfr[ni] = *(const bf16x8*)((const char*)Bs + row * 128 +
                                   ((kk * 64 + lhi * 16) ^ ((l16 & 7) << 4)));
      }
      __builtin_amdgcn_s_setprio(1);
#pragma unroll
      for (int mi = 0; mi < 4; ++mi)
#pragma unroll
        for (int ni = 0; ni < 4; ++ni)
          acc[mi][ni] = MFMA(af[mi], bfr[ni], acc[mi][ni]);
      __builtin_amdgcn_s_setprio(0);
    }
    __syncthreads();
  }

#pragma unroll
  for (int mi = 0; mi < 4; ++mi)
#pragma unroll
    for (int ni = 0; ni < 4; ++ni) {
      int col = n0 + wn * 64 + ni * 16 + l16;
#pragma unroll
      for (int j = 0; j < 4; ++j) {
        int row = m0 + wm * 64 + mi * 16 + lhi * 4 + j;
        float v = acc[mi][ni][j];
        if (OUT_F32)
          ((float*)Cout)[(size_t)row * N + col] = v;
        else
          ((u16*)Cout)[(size_t)row * N + col] = f2bf(v);
      }
    }
}

// ------- RoPE+norm for Q and K, plus sigma-permuted V transpose, ONE launch -------
// blocks [0,16384): Q rope+norm; [16384,20480): K rope+norm; [20480,22528): V transpose.
__global__ __launch_bounds__(256) void rope_tr_qkv(const u16* __restrict__ raw,
                                                   u16* __restrict__ qout,
                                                   u16* __restrict__ kout,
                                                   u16* __restrict__ vt,
                                                   const float* __restrict__ ctab,
                                                   const float* __restrict__ stab,
                                                   const float* __restrict__ gq,
                                                   const float* __restrict__ gk,
                                                   float qscale) {
  __shared__ u16 tile[32][33];
  if (blockIdx.x >= 20480) {
    // ---- V transpose with sigma-permuted columns (64-wide groups) ----
    int f = blockIdx.x - 20480;          // 0..2047; orig grid (x=64,y=4,z=8)
    int t0 = (f & 63) * 32, d0 = ((f >> 6) & 3) * 32;
    int bh = f >> 8;
    int b = bh >> 2, hkk = bh & 3;
    int tx = threadIdx.x & 31, ty = threadIdx.x >> 5;  // ty 0..7
#pragma unroll
    for (int i = 0; i < 4; ++i) {
      int r = ty + i * 8;
      tile[r][tx] = raw[((size_t)(b * 2048 + t0 + r)) * 3072 + 2560 + hkk * 128 + d0 + tx];
    }
    __syncthreads();
#pragma unroll
    for (int i = 0; i < 4; ++i) {
      int r = ty + i * 8;                 // d within 32
      int tg = t0 + tx;                   // actual kv position
      int n = (tg >> 4) & 3, l = tg & 15;
      int colp = (tg & ~63) + l * 2 + (n & 1) + ((n >> 1) << 5);
      vt[((size_t)((b * 4 + hkk) * 128 + d0 + r)) * 2048 + colp] = tile[tx][r];
    }
    return;
  }
  // ---- RoPE + L2 norm + gamma ----
  const bool isQ = blockIdx.x < 16384;
  const int bid = isQ ? blockIdx.x : (blockIdx.x - 16384);
  const int NH = isQ ? 16 : 4;
  const int coloff = isQ ? 0 : 2048;
  const float scale = isQ ? qscale : 1.0f;
  const float* gamma = isQ ? gq : gk;
  u16* out = isQ ? qout : kout;

  int gw = bid * 4 + (threadIdx.x >> 6);
  int lane = threadIdx.x & 63;
  int h = gw & (NH - 1);
  int bt = gw / NH;               // 0..4095
  int t = bt & 2047, bb = bt >> 11;
  const u16* r = raw + (size_t)bt * 3072 + coloff + (size_t)h * 128;
  ushort2 own = *(const ushort2*)(r + 2 * lane);
  int pk = __shfl_xor(__builtin_bit_cast(int, own), 32);
  ushort2 par = __builtin_bit_cast(ushort2, pk);
  float x0 = bf2f(own.x), x1 = bf2f(own.y);
  float y0 = bf2f(par.x), y1 = bf2f(par.y);
  int f = (lane & 31) * 2;
  float2 c2 = *(const float2*)(ctab + t * 64 + f);
  float2 s2 = *(const float2*)(stab + t * 64 + f);
  bool hi = lane >= 32;
  float e0 = hi ? (x0 * c2.x + y0 * s2.x) : (x0 * c2.x - y0 * s2.x);
  float e1 = hi ? (x1 * c2.y + y1 * s2.y) : (x1 * c2.y - y1 * s2.y);
  float ss = e0 * e0 + e1 * e1;
#pragma unroll
  for (int off = 1; off < 64; off <<= 1) ss += __shfl_xor(ss, off);
  float inv = scale / (sqrtf(ss) + 1e-6f);
  float2 g2 = *(const float2*)(gamma + 2 * lane);
  size_t ob = (((size_t)(bb * NH + h)) * 2048 + t) * 128 + 2 * lane;
  ushort2 o = {f2bf(e0 * inv * g2.x), f2bf(e1 * inv * g2.y)};
  *(ushort2*)(out + ob) = o;
}

// ---------------- flash attention, sliding window 1024, QBLK=128, KVBLK=64 ----------------
// (R16/R13-validated version: 80KB LDS, sigma-P packed writes, lazy max.)
__global__ __launch_bounds__(512, 4) void attn_kernel(const u16* __restrict__ Qr,
                                                      const u16* __restrict__ Kr,
                                                      const u16* __restrict__ Vt,
                                                      u16* __restrict__ Yt) {
  __shared__ u16 Ks[2][64 * 128];
  __shared__ u16 Vs[2][128 * 64];
  __shared__ u16 Ps[8][16 * 64];
  const int tid = threadIdx.x;
  const int lane = tid & 63;
  const int wv = tid >> 6;
  const int l16 = lane & 15, lhi = lane >> 4;
  const int work = (blockIdx.x & 7) * 64 + (blockIdx.x >> 3);
  const int q0b = (work & 15) << 7;
  const int bh = work >> 4;
  const int b = bh >> 4, h = bh & 15;
  const int hk = h >> 2;
  const int q0w = q0b + wv * 16;

  const u16* qbase = Qr + (((size_t)bh) * 2048 + q0w + l16) * 128;
  bf16x8 qf[4];
#pragma unroll
  for (int dc = 0; dc < 4; ++dc)
    qf[dc] = *(const bf16x8*)(qbase + dc * 32 + lhi * 8);

  const char* kg = (const char*)(Kr + ((size_t)(b * 4 + hk)) * 2048 * 128);
  const u16* vg = Vt + ((size_t)(b * 4 + hk)) * 2048 * 128;

  auto stage = [&](int buf, int s0) {
#pragma unroll
    for (int i = 0; i < 2; ++i) {
      int c = wv + 8 * i;
      int row = c * 4 + lhi;
      int srcb = (l16 * 16) ^ ((row & 7) << 4);
      gl_lds16(kg + (size_t)(s0 + row) * 256 + srcb, (char*)Ks[buf] + c * 1024);
    }
    int r8 = lane >> 3, c8 = lane & 7;
#pragma unroll
    for (int i = 0; i < 2; ++i) {
      int c = wv + 8 * i;
      int row = c * 8 + r8;
      int srcb = (c8 * 16) ^ ((r8 & 7) << 4);
      gl_lds16((const char*)(vg + (size_t)row * 2048 + s0) + srcb,
               (char*)Vs[buf] + c * 1024);
    }
  };

  const bf16x8 ones = {0x3F80, 0x3F80, 0x3F80, 0x3F80, 0x3F80, 0x3F80, 0x3F80, 0x3F80};
  float mbase = 0.f;
  f32x4 lacc = {};
  f32x4 oacc[8] = {};

  int s_lo = q0b - 1024; if (s_lo < 0) s_lo = 0;
  const int nt = (q0b + 128 - s_lo) >> 6;

  stage(0, s_lo);
  int cur = 0;
  for (int it = 0; it < nt; ++it) {
    const int s0 = s_lo + (it << 6);
    if (it + 1 < nt) {
      stage(cur ^ 1, s0 + 64);
      wait_vmcnt<4>();
    } else {
      wait_vmcnt<0>();
    }
    block_barrier();
    const bool skip = (q0w + 15 < s0) || (q0w - (s0 + 63) > 1024);
    if (!skip) {
      f32x4 sacc[4] = {};
      const char* ksb = (const char*)Ks[cur];
      __builtin_amdgcn_s_setprio(1);
#pragma unroll
      for (int n = 0; n < 4; ++n) {
        int row = n * 16 + l16;
#pragma unroll
        for (int dc = 0; dc < 4; ++dc) {
          bf16x8 kf = *(const bf16x8*)(ksb + row * 256 +
                                       ((dc * 64 + lhi * 16) ^ ((l16 & 7) << 4)));
          sacc[n] = MFMA(qf[dc], kf, sacc[n]);
        }
      }
      __builtin_amdgcn_s_setprio(0);
      const bool domask = (q0w < s0 + 63) || (q0w + 15 - s0 > 1024);
      if (domask) {
#pragma unroll
        for (int n = 0; n < 4; ++n)
#pragma unroll
          for (int j = 0; j < 4; ++j) {
            int q = q0w + lhi * 4 + j;
            int s = s0 + n * 16 + l16;
            if ((unsigned)(q - s) > 1024u) sacc[n][j] = -INFINITY;
          }
      }
      float nm[4];
#pragma unroll
      for (int n = 0; n < 4; ++n)
        nm[n] = fmaxf(fmaxf(sacc[n][0], sacc[n][1]), fmaxf(sacc[n][2], sacc[n][3]));
      float lm = fmaxf(fmaxf(nm[0], nm[1]), fmaxf(nm[2], nm[3]));
      if (__any(lm > mbase + 8.f)) {
        float mt = lm;
#pragma unroll
        for (int off = 1; off < 64; off <<= 1) mt = fmaxf(mt, __shfl_xor(mt, off));
        float sc2 = exp2_hw(mbase - mt);
#pragma unroll
        for (int j = 0; j < 4; ++j) lacc[j] *= sc2;
#pragma unroll
        for (int dt = 0; dt < 8; ++dt)
#pragma unroll
          for (int j = 0; j < 4; ++j) oacc[dt][j] *= sc2;
        mbase = mt;
      }
      char* psb = (char*)Ps[wv];
#pragma unroll
      for (int j = 0; j < 4; ++j) {
        int R = lhi * 4 + j;
        float p0 = exp2_hw(sacc[0][j] - mbase);
        float p1 = exp2_hw(sacc[1][j] - mbase);
        float p2 = exp2_hw(sacc[2][j] - mbase);
        float p3 = exp2_hw(sacc[3][j] - mbase);
        unsigned r01, r23;
        asm("v_cvt_pk_bf16_f32 %0, %1, %2" : "=v"(r01) : "v"(p0), "v"(p1));
        asm("v_cvt_pk_bf16_f32 %0, %1, %2" : "=v"(r23) : "v"(p2), "v"(p3));
        *(unsigned*)(psb + R * 128 + ((l16 * 4) ^ ((R & 7) << 4))) = r01;
        *(unsigned*)(psb + R * 128 + ((64 + l16 * 4) ^ ((R & 7) << 4))) = r23;
      }
      bf16x8 pf[2];
#pragma unroll
      for (int kk = 0; kk < 2; ++kk)
        pf[kk] = *(const bf16x8*)(psb + l16 * 128 +
                                  ((kk * 64 + lhi * 16) ^ ((l16 & 7) << 4)));
      const char* vsb = (const char*)Vs[cur];
      __builtin_amdgcn_s_setprio(1);
      lacc = MFMA(pf[0], ones, lacc);
      lacc = MFMA(pf[1], ones, lacc);
#pragma unroll
      for (int dt = 0; dt < 8; ++dt) {
        int row = dt * 16 + l16;
#pragma unroll
        for (int kk = 0; kk < 2; ++kk) {
          bf16x8 vf = *(const bf16x8*)(vsb + row * 128 +
                                       ((kk * 64 + lhi * 16) ^ ((l16 & 7) << 4)));
          oacc[dt] = MFMA(pf[kk], vf, oacc[dt]);
        }
      }
      __builtin_amdgcn_s_setprio(0);
    }
    block_barrier();
    cur ^= 1;
  }
#pragma unroll
  for (int j = 0; j < 4; ++j) {
    float inv = 1.0f / lacc[j];
    int q = q0w + lhi * 4 + j;
    size_t rowbase = ((size_t)(b * 2048 + q)) * 2048 + (size_t)h * 128;
#pragma unroll
    for (int dt = 0; dt < 8; ++dt)
      Yt[rowbase + dt * 16 + l16] = f2bf(oacc[dt][j] * inv);
  }
}

extern "C" void kernel_launch(void* const* d_in, const int* in_sizes, int n_in,
                              void* d_out, int out_size, void* d_ws, size_t ws_size,
                              hipStream_t stream) {
  (void)in_sizes; (void)n_in; (void)out_size; (void)ws_size;
  const float* x  = (const float*)d_in[0];
  const float* wq = (const float*)d_in[1];
  const float* wk = (const float*)d_in[2];
  const float* wv = (const float*)d_in[3];
  const float* wo = (const float*)d_in[4];
  const float* gq = (const float*)d_in[5];
  const float* gk = (const float*)d_in[6];
  float* out = (float*)d_out;
  char* ws = (char*)d_ws;

  size_t off = 0;
  auto alloc = [&](size_t bytes) {
    size_t o = off;
    off += (bytes + 255) & ~(size_t)255;
    return o;
  };
  u16* xb     = (u16*)(ws + alloc((size_t)4096 * 2048 * 2));
  u16* wqkvb  = (u16*)(ws + alloc((size_t)3072 * 2048 * 2));
  u16* wob    = (u16*)(ws + alloc((size_t)2048 * 2048 * 2));
  u16* qkvraw = (u16*)(ws + alloc((size_t)4096 * 3072 * 2));  // later reused as ytmp
  u16* qr     = (u16*)(ws + alloc((size_t)4096 * 2048 * 2));
  u16* kr     = (u16*)(ws + alloc((size_t)4096 * 512 * 2));
  u16* vt     = (u16*)(ws + alloc((size_t)4096 * 512 * 2));
  float* ctab = (float*)(ws + alloc((size_t)2048 * 64 * 4));
  float* stab = (float*)(ws + alloc((size_t)2048 * 64 * 4));
  u16* ytmp = qkvraw;  // safe: qkvraw fully consumed before attn writes

  const float sc_log2 = 0.12751744f;  // 1/sqrt(128) * log2(e)

  cvt_all<<<18688, 256, 0, stream>>>(x, wq, wk, wv, wo, xb, wqkvb, wob, ctab, stab);

  // fused QKV projection (XCD-swizzled 1D grid: 768 blocks)
  gemm_m97<0><<<768, 256, 0, stream>>>(xb, wqkvb, qkvraw, 4096, 3072, 2048);

  // RoPE+norm (Q,K) + sigma-permuted V transpose, one launch
  rope_tr_qkv<<<22528, 256, 0, stream>>>(qkvraw, qr, kr, vt, ctab, stab, gq, gk, sc_log2);

  attn_kernel<<<dim3(512), 512, 0, stream>>>(qr, kr, vt, ytmp);

  // output projection (f32 out; XCD-swizzled 1D grid: 512 blocks)
  gemm_m97<1><<<512, 256, 0, stream>>>(ytmp, wob, out, 4096, 2048, 2048);
}